// Round 3
// baseline (360.633 us; speedup 1.0000x reference)
//
#include <hip/hip_runtime.h>

// SMPL GAT encoder, fully fused, one node per thread.
// Graph insight: self-loops + tree edges => each destination has <=2 in-edges
// (self + parent) => segment softmax is a 2-way softmax.
// Weights are wave-uniform loads (s_load -> SGPR operands, scalar cache); the
// LDS pipe only carries the per-node h exchange + store staging.
//
// R1: coalesced epilogue stores via LDS re-staging. 401.8 -> 359.8 us.
// R2: persistent blocks + src register prefetch. NEUTRAL (360.3) -> latency /
//     turnover is not the bottleneck.
// R3: raw s_barrier with lgkmcnt-only waits (T4 pattern). __syncthreads()
//     emits s_waitcnt vmcnt(0) before s_barrier, draining the tile's 18 KB
//     store burst (and the src prefetch) at EVERY barrier -> phase
//     serialization. Raw barriers let stores stay in flight across B4 and
//     hide under the next tile's k-loop. LDS correctness kept via explicit
//     s_waitcnt lgkmcnt(0) before each barrier.

#define JNT 24               // joints per frame
#define FPB 8                // frames per block-tile
#define TPB (FPB*JNT)        // 192 threads = 3 waves
#define NPB (FPB*JNT)        // 192 nodes per tile (1 per thread)
#define NT  16384            // total tiles = 64*2048/FPB
#define GRID 1280            // 5 blocks/CU * 256 CU (LDS+waveslot concurrent residency)

// SMPL parent table
__constant__ int c_par[JNT] = {-1,0,0,0,1,2,3,4,5,6,7,8,9,9,9,12,13,14,16,17,18,19,20,21};

// swizzled row offset for s_h: stride 28 dwords, +4 dwords every 8 rows.
__device__ __forceinline__ int hoff(int r) { return r*28 + ((r>>3)<<2); }

#define SH_SIZE 5468   // hoff(NPB-1)+28; also >= stage region 191*28+24

// Raw barrier: LDS visibility only (lgkmcnt(0)), NO vmcnt drain -> global
// stores/loads stay in flight across the barrier.
#define BAR() do { asm volatile("s_waitcnt lgkmcnt(0)" ::: "memory"); \
                   __builtin_amdgcn_s_barrier(); } while (0)

__global__ __launch_bounds__(TPB, 4)
void gat_encoder(const float* __restrict__ src,
                 const float* __restrict__ W_pre,
                 const float* __restrict__ b_pre,
                 const float* __restrict__ W_gat,
                 const float* __restrict__ att_src,
                 const float* __restrict__ att_dst,
                 const float* __restrict__ b_gat,
                 float* __restrict__ out)
{
    __shared__ int   s_par[JNT];
    __shared__ __align__(16) float s_h[SH_SIZE];   // h[0..23]+a_src[24..26] per node; reused for out staging

    const int tid = threadIdx.x;
    if (tid < JNT) s_par[tid] = c_par[tid];        // consumed after first B1

    int tile = blockIdx.x;

    // prefetch tile 0's src (per-thread 12 B, wave = contiguous 768 B)
    const float* sg = src + (size_t)tile * (NPB*3) + tid*3;
    float p0 = sg[0], p1 = sg[1], p2 = sg[2];

    while (tile < NT) {
        // ---- issue next tile's loads (hidden under this tile's compute) ----
        const int nxt = tile + GRID;
        const float* ng = src + (size_t)(nxt < NT ? nxt : tile) * (NPB*3) + tid*3;
        float q0 = ng[0], q1 = ng[1], q2 = ng[2];

        // ---- h = relu(src*W_pre + b_pre) * W_gat, x kept transient ----
        float h[JNT];
        #pragma unroll
        for (int o = 0; o < JNT; ++o) h[o] = 0.f;

        #pragma unroll 2
        for (int k = 0; k < JNT; ++k) {
            // wave-uniform loads -> s_load -> SGPR operands
            const float w0 = W_pre[k], w1 = W_pre[24+k], w2 = W_pre[48+k];
            const float bb = b_pre[k];
            float x = fmaf(p0, w0, fmaf(p1, w1, fmaf(p2, w2, bb)));
            x = fmaxf(x, 0.f);
            #pragma unroll
            for (int o = 0; o < JNT; ++o)
                h[o] = fmaf(x, W_gat[k*JNT + o], h[o]);
        }

        // ---- attention dots (att vectors uniform -> SGPRs) ----
        float as[3], ad[3];
        #pragma unroll
        for (int hd = 0; hd < 3; ++hd) {
            float a = 0.f, d = 0.f;
            #pragma unroll
            for (int o = 0; o < 8; ++o) {
                a = fmaf(h[hd*8+o], att_src[hd*8+o], a);
                d = fmaf(h[hd*8+o], att_dst[hd*8+o], d);
            }
            as[hd] = a; ad[hd] = d;
        }

        // ---- publish h + a_src for children ----
        float* hr = &s_h[hoff(tid)];
        #pragma unroll
        for (int q = 0; q < 6; ++q)
            ((float4*)hr)[q] = make_float4(h[q*4+0], h[q*4+1], h[q*4+2], h[q*4+3]);
        hr[24] = as[0]; hr[25] = as[1]; hr[26] = as[2];
        BAR();                                         // B1: publish visible (lgkm only)

        // ---- 2-way softmax vs parent ----
        const int  f    = tid / JNT;
        const int  j    = tid - f*JNT;
        const int  par  = s_par[j];
        const bool hasp = (par >= 0);
        const float* hp = &s_h[hoff(f*JNT + (hasp ? par : j))];

        float ws[3], wpv[3];
        #pragma unroll
        for (int hd = 0; hd < 3; ++hd) {
            float es = as[hd] + ad[hd];      es = es < 0.f ? 0.2f*es : es;
            float ep = hp[24+hd] + ad[hd];   ep = ep < 0.f ? 0.2f*ep : ep;
            float m  = hasp ? fmaxf(es, ep) : es;
            float e1 = __expf(es - m);
            float e2 = hasp ? __expf(ep - m) : 0.f;
            float r  = 1.f / (e1 + e2);
            ws[hd] = e1*r; wpv[hd] = e2*r;
        }

        // ---- blend, bias (uniform), relu -> registers ----
        float r[JNT];
        #pragma unroll
        for (int q = 0; q < 6; ++q) {
            const int hd = q >> 1;
            const float4 p4 = ((const float4*)hp)[q];
            r[q*4+0] = fmaxf(fmaf(wpv[hd], p4.x, fmaf(ws[hd], h[q*4+0], b_gat[q*4+0])), 0.f);
            r[q*4+1] = fmaxf(fmaf(wpv[hd], p4.y, fmaf(ws[hd], h[q*4+1], b_gat[q*4+1])), 0.f);
            r[q*4+2] = fmaxf(fmaf(wpv[hd], p4.z, fmaf(ws[hd], h[q*4+2], b_gat[q*4+2])), 0.f);
            r[q*4+3] = fmaxf(fmaf(wpv[hd], p4.w, fmaf(ws[hd], h[q*4+3], b_gat[q*4+3])), 0.f);
        }

        BAR();                                         // B2: all parent-h reads done; s_h reusable
        {
            float* orow = &s_h[tid*28];
            #pragma unroll
            for (int q = 0; q < 6; ++q)
                ((float4*)orow)[q] = make_float4(r[q*4+0], r[q*4+1], r[q*4+2], r[q*4+3]);
        }
        BAR();                                         // B3: staging visible

        // ---- staged read -> regs, then coalesced stores (left in flight) ----
        {
            const int n0 = (tid*4) / JNT;        // float4 never straddles a node (24 | 4-chunks)
            const int c0 = (tid*4) % JNT;
            const float* rb = &s_h[n0*28 + c0];
            float4 v[6];
            #pragma unroll
            for (int k = 0; k < 6; ++k)
                v[k] = *(const float4*)(rb + k*896);   // 32 nodes * 28 dwords
            float* og = out + (size_t)tile * (NPB*JNT) + tid*4;
            #pragma unroll
            for (int k = 0; k < 6; ++k)
                *(float4*)(og + k*768) = v[k];         // lane-contiguous 1 KB per wave-instr
        }

        BAR();   // B4: lgkm only -> staged reads complete everywhere; stores STAY in flight
        p0 = q0; p1 = q1; p2 = q2;
        tile = nxt;
    }
}

extern "C" void kernel_launch(void* const* d_in, const int* in_sizes, int n_in,
                              void* d_out, int out_size, void* d_ws, size_t ws_size,
                              hipStream_t stream) {
    const float* src     = (const float*)d_in[0];
    const float* W_pre   = (const float*)d_in[1];
    const float* b_pre   = (const float*)d_in[2];
    const float* W_gat   = (const float*)d_in[3];
    const float* att_src = (const float*)d_in[4];
    const float* att_dst = (const float*)d_in[5];
    const float* b_gat   = (const float*)d_in[6];
    float* out = (float*)d_out;

    gat_encoder<<<dim3(GRID), dim3(TPB), 0, stream>>>(
        src, W_pre, b_pre, W_gat, att_src, att_dst, b_gat, out);
}

// Round 4
// 359.839 us; speedup vs baseline: 1.0022x; 1.0022x over previous
//
#include <hip/hip_runtime.h>

// SMPL GAT encoder, fully fused. One WAVE per block, 2 frames per wave.
// Graph insight: self-loops + tree edges => each destination has <=2 in-edges
// (self + parent) => segment softmax is a 2-way softmax.
//
// R1: coalesced epilogue stores via LDS re-staging. 401.8 -> 359.8 us.
// R2: persistent blocks + src prefetch. NEUTRAL -> latency not the limiter.
// R3: lgkm-only barriers (no vmcnt drain). NEUTRAL -> barrier drain not the
//     limiter either.
// R4: (a) single-wave blocks: 2 frames per 64-lane wave (lanes 48-63 idle in
//     compute, all 64 used in the store phase). Frames never straddle waves
//     -> every barrier is intra-wave (near-free), LDS exchange wave-local,
//     16 independent blocks/CU for phase overlap.
//     (b) packed-f32 math: h-GEMM / attention dots / blend on float2 vectors
//     -> v_pk_fma_f32 (dual FMA per lane-cycle), ~halves the dominant VALU.

typedef float f32x2 __attribute__((ext_vector_type(2)));

#define JNT 24               // joints per frame
#define FPW 2                // frames per wave/block
#define TPB 64               // one wave
#define ACT (FPW*JNT)        // 48 active lanes / nodes per block
#define OUTD (ACT*JNT)       // 1152 output dwords per block

// SMPL parent table
__constant__ int c_par[JNT] = {-1,0,0,0,1,2,3,4,5,6,7,8,9,9,9,12,13,14,16,17,18,19,20,21};

// swizzled row offset: stride 28 dwords, +4 dwords every 8 rows.
// Per-8-lane group covers all 32 banks exactly once for b128 ops.
__device__ __forceinline__ int hoff(int r) { return r*28 + ((r>>3)<<2); }

#define SH_SIZE 1364   // hoff(47)+28

// Intra-wave barrier: LDS visibility only (lgkmcnt(0)), no vmcnt drain.
#define BAR() do { asm volatile("s_waitcnt lgkmcnt(0)" ::: "memory"); \
                   __builtin_amdgcn_s_barrier(); } while (0)

__global__ __launch_bounds__(TPB, 4)
void gat_encoder(const float* __restrict__ src,
                 const float* __restrict__ W_pre,
                 const float* __restrict__ b_pre,
                 const float* __restrict__ W_gat,
                 const float* __restrict__ att_src,
                 const float* __restrict__ att_dst,
                 const float* __restrict__ b_gat,
                 float* __restrict__ out)
{
    __shared__ int   s_par[JNT];
    __shared__ __align__(16) float s_h[SH_SIZE];  // h[0..23]+a_src[24..26] per node; reused for out staging

    const int tid = threadIdx.x;
    const int blk = blockIdx.x;
    const bool act = tid < ACT;

    if (tid < JNT) s_par[tid] = c_par[tid];

    f32x2 h2[12];
    float as[3], ad[3];

    if (act) {
        // per-node input (12 B/lane, contiguous 576 B per block)
        const float* sg = src + (size_t)blk * (ACT*3) + tid*3;
        const float p0 = sg[0], p1 = sg[1], p2 = sg[2];

        #pragma unroll
        for (int o = 0; o < 12; ++o) h2[o] = (f32x2){0.f, 0.f};

        // ---- h = relu(src*W_pre + b_pre) * W_gat (packed dual-FMA) ----
        #pragma unroll 2
        for (int k = 0; k < JNT; ++k) {
            const float w0 = W_pre[k], w1 = W_pre[24+k], w2 = W_pre[48+k];
            const float bb = b_pre[k];
            float x = fmaf(p0, w0, fmaf(p1, w1, fmaf(p2, w2, bb)));
            x = fmaxf(x, 0.f);
            const f32x2 xx = (f32x2){x, x};
            const f32x2* wr = (const f32x2*)(W_gat + k*JNT);   // wave-uniform -> s_load
            #pragma unroll
            for (int o = 0; o < 12; ++o)
                h2[o] = xx * wr[o] + h2[o];                     // v_pk_fma_f32
        }

        // ---- attention dots ----
        #pragma unroll
        for (int hd = 0; hd < 3; ++hd) {
            f32x2 a2 = (f32x2){0.f, 0.f}, d2 = (f32x2){0.f, 0.f};
            const f32x2* asr = (const f32x2*)(att_src + hd*8);
            const f32x2* adr = (const f32x2*)(att_dst + hd*8);
            #pragma unroll
            for (int o = 0; o < 4; ++o) {
                a2 = h2[hd*4+o] * asr[o] + a2;
                d2 = h2[hd*4+o] * adr[o] + d2;
            }
            as[hd] = a2.x + a2.y;
            ad[hd] = d2.x + d2.y;
        }

        // ---- publish h + a_src ----
        float* hr = &s_h[hoff(tid)];
        #pragma unroll
        for (int q = 0; q < 6; ++q)
            ((float4*)hr)[q] = make_float4(h2[2*q].x, h2[2*q].y, h2[2*q+1].x, h2[2*q+1].y);
        hr[24] = as[0]; hr[25] = as[1]; hr[26] = as[2];
    }
    BAR();   // intra-wave: publish visible

    f32x2 r2[12];
    if (act) {
        const int  f    = tid >= JNT;            // frame within block (0/1)
        const int  j    = tid - f*JNT;
        const int  par  = s_par[j];
        const bool hasp = (par >= 0);
        const float* hp = &s_h[hoff(f*JNT + (hasp ? par : j))];

        // ---- 2-way softmax vs parent ----
        float ws[3], wpv[3];
        #pragma unroll
        for (int hd = 0; hd < 3; ++hd) {
            float es = as[hd] + ad[hd];      es = es < 0.f ? 0.2f*es : es;
            float ep = hp[24+hd] + ad[hd];   ep = ep < 0.f ? 0.2f*ep : ep;
            float m  = hasp ? fmaxf(es, ep) : es;
            float e1 = __expf(es - m);
            float e2 = hasp ? __expf(ep - m) : 0.f;
            float r  = 1.f / (e1 + e2);
            ws[hd] = e1*r; wpv[hd] = e2*r;
        }

        // ---- blend, bias, relu (packed) ----
        const f32x2* bg = (const f32x2*)b_gat;
        #pragma unroll
        for (int q = 0; q < 6; ++q) {
            const int hd = q >> 1;
            const float4 p4 = ((const float4*)hp)[q];
            const f32x2 wsv = (f32x2){ws[hd],  ws[hd]};
            const f32x2 wp2 = (f32x2){wpv[hd], wpv[hd]};
            f32x2 t0 = (f32x2){p4.x, p4.y};
            f32x2 t1 = (f32x2){p4.z, p4.w};
            f32x2 a = wp2 * t0 + (wsv * h2[2*q]   + bg[2*q]);
            f32x2 b = wp2 * t1 + (wsv * h2[2*q+1] + bg[2*q+1]);
            a.x = fmaxf(a.x, 0.f); a.y = fmaxf(a.y, 0.f);
            b.x = fmaxf(b.x, 0.f); b.y = fmaxf(b.y, 0.f);
            r2[2*q] = a; r2[2*q+1] = b;
        }
    }
    BAR();   // parent-h reads complete; s_h reusable

    if (act) {
        float* orow = &s_h[hoff(tid)];
        #pragma unroll
        for (int q = 0; q < 6; ++q)
            ((float4*)orow)[q] = make_float4(r2[2*q].x, r2[2*q].y, r2[2*q+1].x, r2[2*q+1].y);
    }
    BAR();   // staging visible

    // ---- coalesced chunked stores: 288 float4 chunks, all 64 lanes ----
    // chunk c covers out dwords [4c, 4c+4); node rows are 24 dwords (mult of
    // 4) so a chunk never straddles a node row.
    {
        float* og = out + (size_t)blk * OUTD;
        #pragma unroll
        for (int k = 0; k < 4; ++k) {
            const int c  = k*64 + tid;
            const int n0 = (c*4) / JNT;
            const int o0 = (c*4) - n0*JNT;
            const float4 v = *(const float4*)&s_h[hoff(n0) + o0];
            ((float4*)og)[c] = v;
        }
        if (tid < 32) {
            const int c  = 256 + tid;
            const int n0 = (c*4) / JNT;
            const int o0 = (c*4) - n0*JNT;
            const float4 v = *(const float4*)&s_h[hoff(n0) + o0];
            ((float4*)og)[c] = v;
        }
    }
}

extern "C" void kernel_launch(void* const* d_in, const int* in_sizes, int n_in,
                              void* d_out, int out_size, void* d_ws, size_t ws_size,
                              hipStream_t stream) {
    const float* src     = (const float*)d_in[0];
    const float* W_pre   = (const float*)d_in[1];
    const float* b_pre   = (const float*)d_in[2];
    const float* W_gat   = (const float*)d_in[3];
    const float* att_src = (const float*)d_in[4];
    const float* att_dst = (const float*)d_in[5];
    const float* b_gat   = (const float*)d_in[6];
    float* out = (float*)d_out;

    const int frames = 64 * 2048;          // N * L
    const int blocks = frames / FPW;       // 65536 single-wave blocks
    gat_encoder<<<dim3(blocks), dim3(TPB), 0, stream>>>(
        src, W_pre, b_pre, W_gat, att_src, att_dst, b_gat, out);
}